// Round 9
// baseline (599.110 us; speedup 1.0000x reference)
//
#include <hip/hip_runtime.h>

// GridManifoldNetwork, round 9: spatial bucket-sort for wave-level coalescing.
//
// Model (fits R3/R6/R8 neutral results): all kernels sit at a chip-wide
// random-request wall ~0.235M lane-req/us; total inventory ~84M req = 357us.
// Only lever: reduce requests. TA merges same-64B-line lanes WITHIN one
// instruction -> sort points into 32^3 spatial buckets (~64 pts = 1 wave per
// bucket) so corner-gather instructions have many duplicate/same-line lanes:
// level1 x0.06, level2 x0.13, hash L3 x0.64, L4 x0.94, L5 x0.99.
// Sort = hist (atomics) + 1-block scan + atomic scatter; out via perm.
// Per-point math unchanged -> absmax identical to R7/R8.
//
// Levels: res=16,32,64,128,256,512; F=2; T=2^19; levels 3..5 hashed,
// size 2^19 -> & 0x7FFFF. Entry offsets: 0,4096,36864,299008,823296,1347584.

#define HP1 2654435761u
#define HP2 805459861u
#define HMASK ((1u << 19) - 1u)
#define NBUCK 32768

static __device__ __forceinline__ unsigned umin_(unsigned a, unsigned b) {
    return a < b ? a : b;
}

// bf16 round-to-nearest-even pack/unpack.
static __device__ __forceinline__ unsigned f2bf(float f) {
    unsigned u = __float_as_uint(f);
    return (u + 0x7fffu + ((u >> 16) & 1u)) >> 16;
}
static __device__ __forceinline__ float bf2f_lo(unsigned p) {
    return __uint_as_float((p & 0xffffu) << 16);
}
static __device__ __forceinline__ float bf2f_hi(unsigned p) {
    return __uint_as_float(p & 0xffff0000u);
}

static __device__ __forceinline__ unsigned bucket_of(float px, float py, float pz) {
    const float xn0 = (px + 1.0f) * 0.5f;
    const float xn1 = (py + 1.0f) * 0.5f;
    const float xn2 = (pz + 1.0f) * 0.5f;
    const unsigned qx = umin_((unsigned)(xn0 * 32.0f), 31u);
    const unsigned qy = umin_((unsigned)(xn1 * 32.0f), 31u);
    const unsigned qz = umin_((unsigned)(xn2 * 32.0f), 31u);
    return qz * 1024u + qy * 32u + qx;
}

// Prep: wt[0..1023] = W0T rows (wt[j*16+i] = W0[i*64+j], i=15 -> b0[j]);
// wt[1024..1087] = W1; wt[1088] = b1.
__global__ __launch_bounds__(256) void prep_kernel(
    const float* __restrict__ W0, const float* __restrict__ b0,
    const float* __restrict__ W1, const float* __restrict__ b1,
    float* __restrict__ wt)
{
    for (int t = threadIdx.x; t < 1024; t += 256) {
        const int j = t >> 4, i = t & 15;
        wt[t] = (i == 15) ? b0[j] : W0[i * 64 + j];
    }
    if (threadIdx.x < 64) wt[1024 + threadIdx.x] = W1[threadIdx.x];
    if (threadIdx.x == 0) wt[1088] = b1[0];
}

__global__ __launch_bounds__(256) void hist_kernel(
    const float* __restrict__ x, unsigned* __restrict__ hist, int N)
{
    const int g = blockIdx.x * 256 + threadIdx.x;
    if (g >= N) return;
    const unsigned b = bucket_of(x[3 * g], x[3 * g + 1], x[3 * g + 2]);
    atomicAdd(&hist[b], 1u);
}

// In-place exclusive scan of hist[NBUCK], single block of 256 threads.
__global__ __launch_bounds__(256) void scan_kernel(unsigned* __restrict__ hist)
{
    __shared__ unsigned ssum[256];
    const int t = threadIdx.x;
    constexpr int CH = NBUCK / 256;   // 128 per thread
    unsigned s = 0;
    for (int i = 0; i < CH; ++i) s += hist[t * CH + i];
    ssum[t] = s;
    __syncthreads();
    if (t == 0) {
        unsigned run = 0;
        for (int i = 0; i < 256; ++i) { unsigned v = ssum[i]; ssum[i] = run; run += v; }
    }
    __syncthreads();
    unsigned run = ssum[t];
    for (int i = 0; i < CH; ++i) {
        const unsigned v = hist[t * CH + i];
        hist[t * CH + i] = run;
        run += v;
    }
}

// Scatter points into bucket order; cursor == scanned hist (consumed here).
__global__ __launch_bounds__(256) void scatter_kernel(
    const float* __restrict__ x, unsigned* __restrict__ cursor,
    float* __restrict__ sx, unsigned* __restrict__ perm, int N)
{
    const int g = blockIdx.x * 256 + threadIdx.x;
    if (g >= N) return;
    const float px = x[3 * g], py = x[3 * g + 1], pz = x[3 * g + 2];
    const unsigned b = bucket_of(px, py, pz);
    const unsigned pos = atomicAdd(&cursor[b], 1u);
    __builtin_nontemporal_store(px, sx + 3 * pos + 0);
    __builtin_nontemporal_store(py, sx + 3 * pos + 1);
    __builtin_nontemporal_store(pz, sx + 3 * pos + 2);
    __builtin_nontemporal_store((unsigned)g, perm + pos);
}

// One hashed level: 8 divergent 8B gathers from a 4MB L2-resident table.
// With sorted input, same-cell lanes coalesce within each gather instr.
__global__ __launch_bounds__(256) void hash_level_kernel(
    const float* __restrict__ x,
    const float2* __restrict__ tab,
    unsigned* __restrict__ feat,      // packed bf16x2 per point
    float scale, int N)
{
    const int gid = blockIdx.x * 256 + threadIdx.x;
    if (gid >= N) return;

    const float px = __builtin_nontemporal_load(x + 3 * gid + 0);
    const float py = __builtin_nontemporal_load(x + 3 * gid + 1);
    const float pz = __builtin_nontemporal_load(x + 3 * gid + 2);

    const float p0 = fmaf((px + 1.0f) * 0.5f, scale, 0.5f);
    const float p1 = fmaf((py + 1.0f) * 0.5f, scale, 0.5f);
    const float p2 = fmaf((pz + 1.0f) * 0.5f, scale, 0.5f);
    const float g0 = floorf(p0), g1 = floorf(p1), g2 = floorf(p2);
    const float f0 = p0 - g0, f1 = p1 - g1, f2 = p2 - g2;
    const unsigned i0 = (unsigned)g0, i1 = (unsigned)g1, i2 = (unsigned)g2;

    const float wx[2] = {1.0f - f0, f0};
    const float wy[2] = {1.0f - f1, f1};
    const float wz[2] = {1.0f - f2, f2};
    const unsigned hx[2] = {i0, i0 + 1u};
    const unsigned hy[2] = {i1 * HP1, (i1 + 1u) * HP1};
    const unsigned hz[2] = {i2 * HP2, (i2 + 1u) * HP2};

    unsigned idx[8];
    float w[8];
    #pragma unroll
    for (int c = 0; c < 8; ++c) {
        const int bx = c & 1, by = (c >> 1) & 1, bz = (c >> 2) & 1;
        idx[c] = (hx[bx] ^ hy[by] ^ hz[bz]) & HMASK;
        w[c] = wx[bx] * wy[by] * wz[bz];
    }
    float2 v[8];
    #pragma unroll
    for (int c = 0; c < 8; ++c) v[c] = tab[idx[c]];

    float a0 = 0.0f, a1 = 0.0f;
    #pragma unroll
    for (int c = 0; c < 8; ++c) {
        a0 = fmaf(w[c], v[c].x, a0);
        a1 = fmaf(w[c], v[c].y, a1);
    }
    __builtin_nontemporal_store(f2bf(a0) | (f2bf(a1) << 16), feat + gid);
}

// Dense trilinear level from global; sorted input -> lanes share lines.
static __device__ __forceinline__ void dense_level(
    const float2* __restrict__ tab, unsigned res,
    float xn0, float xn1, float xn2, float& o0, float& o1)
{
    const float scale = (float)(res - 1);
    const float p0 = fmaf(xn0, scale, 0.5f);
    const float p1 = fmaf(xn1, scale, 0.5f);
    const float p2 = fmaf(xn2, scale, 0.5f);
    const float g0 = floorf(p0), g1 = floorf(p1), g2 = floorf(p2);
    const float f0 = p0 - g0, f1 = p1 - g1, f2 = p2 - g2;
    const unsigned i0 = (unsigned)g0, i1 = (unsigned)g1, i2 = (unsigned)g2;

    const unsigned rm1 = res - 1u;
    const unsigned cx[2] = {umin_(i0, rm1), umin_(i0 + 1u, rm1)};
    const unsigned cy[2] = {umin_(i1, rm1) * res, umin_(i1 + 1u, rm1) * res};
    const unsigned cz[2] = {umin_(i2, rm1) * res * res,
                            umin_(i2 + 1u, rm1) * res * res};
    const float wx[2] = {1.0f - f0, f0};
    const float wy[2] = {1.0f - f1, f1};
    const float wz[2] = {1.0f - f2, f2};

    float a0 = 0.0f, a1 = 0.0f;
    #pragma unroll
    for (int c = 0; c < 8; ++c) {
        const int bx = c & 1, by = (c >> 1) & 1, bz = (c >> 2) & 1;
        const unsigned idx = cx[bx] + cy[by] + cz[bz];
        const float w = wx[bx] * wy[by] * wz[bz];
        const float2 v = tab[idx];
        a0 = fmaf(w, v.x, a0);
        a1 = fmaf(w, v.y, a1);
    }
    o0 = a0;
    o1 = a1;
}

// Dense levels 0..2 + MLP(15->64->1), 4 points/thread, zero LDS (R7
// structure: VGPR 36, occ 53%); out scattered via perm (or direct).
__global__ __launch_bounds__(256, 4) void dense_mlp_kernel(
    const float* __restrict__ x,
    const float* __restrict__ grid,
    const unsigned* __restrict__ feat,   // [3][N] packed bf16x2
    const float* __restrict__ wt,        // 1089 floats, see prep_kernel
    const unsigned* __restrict__ perm,   // nullptr -> identity
    float* __restrict__ out, int N)
{
    const int tid = threadIdx.x;
    const int base = blockIdx.x * 1024 + tid;
    const float2* gtab = (const float2*)grid;

    float h[4][16];

    #pragma unroll
    for (int k = 0; k < 4; ++k) {
        const int g = base + 256 * k;
        const int gs = (g < N) ? g : 0;

        const float px = __builtin_nontemporal_load(x + 3 * gs + 0);
        const float py = __builtin_nontemporal_load(x + 3 * gs + 1);
        const float pz = __builtin_nontemporal_load(x + 3 * gs + 2);
        const float xn0 = (px + 1.0f) * 0.5f;
        const float xn1 = (py + 1.0f) * 0.5f;
        const float xn2 = (pz + 1.0f) * 0.5f;

        h[k][0] = px; h[k][1] = py; h[k][2] = pz;
        h[k][15] = 1.0f;

        dense_level(gtab + 0u,     16u, xn0, xn1, xn2, h[k][3], h[k][4]);
        dense_level(gtab + 4096u,  32u, xn0, xn1, xn2, h[k][5], h[k][6]);
        dense_level(gtab + 36864u, 64u, xn0, xn1, xn2, h[k][7], h[k][8]);

        #pragma unroll
        for (int l = 0; l < 3; ++l) {
            const unsigned p = __builtin_nontemporal_load(
                feat + (size_t)l * N + gs);
            h[k][9 + 2 * l]  = bf2f_lo(p);
            h[k][10 + 2 * l] = bf2f_hi(p);
        }
    }

    const float b1v = wt[1088];
    float o[4] = {b1v, b1v, b1v, b1v};

    #pragma unroll 4
    for (int j = 0; j < 64; ++j) {
        float r[16];
        #pragma unroll
        for (int i = 0; i < 16; ++i)
            r[i] = wt[j * 16 + i];          // uniform -> s_load (SMEM pipe)
        const float w1j = wt[1024 + j];
        #pragma unroll
        for (int k = 0; k < 4; ++k) {
            float s = 0.0f;
            #pragma unroll
            for (int i = 0; i < 16; ++i)
                s = fmaf(h[k][i], r[i], s);  // v_fma with SGPR weight
            s = fmaxf(s, 0.0f);
            o[k] = fmaf(s, w1j, o[k]);
        }
    }

    #pragma unroll
    for (int k = 0; k < 4; ++k) {
        const int g = base + 256 * k;
        if (g < N) {
            const int d = perm ? (int)perm[g] : g;
            __builtin_nontemporal_store(o[k], out + d);
        }
    }
}

extern "C" void kernel_launch(void* const* d_in, const int* in_sizes, int n_in,
                              void* d_out, int out_size, void* d_ws, size_t ws_size,
                              hipStream_t stream) {
    const float* x    = (const float*)d_in[0];
    const float* grid = (const float*)d_in[1];
    const float* W0   = (const float*)d_in[2];
    const float* b0   = (const float*)d_in[3];
    const float* W1   = (const float*)d_in[4];
    const float* b1   = (const float*)d_in[5];
    float* out = (float*)d_out;

    const int N = in_sizes[0] / 3;
    const int blocks1 = (N + 255) / 256;
    const int blocks4 = (N + 1023) / 1024;

    const float2* gtab = (const float2*)grid;

    // Workspace layout (feat & wt first so the no-sort fallback shares them).
    auto align256 = [](size_t v) { return (v + 255) & ~(size_t)255; };
    size_t off = 0;
    const size_t feat_off = off; off += align256((size_t)3 * N * 4);
    const size_t wt_off   = off; off += align256(1089 * 4);
    const size_t sx_off   = off; off += align256((size_t)3 * N * 4);
    const size_t perm_off = off; off += align256((size_t)N * 4);
    const size_t hist_off = off; off += align256(NBUCK * 4);
    const bool do_sort = (ws_size >= off);

    unsigned* feat = (unsigned*)((char*)d_ws + feat_off);
    float*    wt   = (float*)((char*)d_ws + wt_off);
    float*    sx   = (float*)((char*)d_ws + sx_off);
    unsigned* perm = (unsigned*)((char*)d_ws + perm_off);
    unsigned* hist = (unsigned*)((char*)d_ws + hist_off);

    prep_kernel<<<1, 256, 0, stream>>>(W0, b0, W1, b1, wt);

    const float* px = x;
    const unsigned* pperm = nullptr;
    if (do_sort) {
        hipMemsetAsync(hist, 0, NBUCK * 4, stream);
        hist_kernel<<<blocks1, 256, 0, stream>>>(x, hist, N);
        scan_kernel<<<1, 256, 0, stream>>>(hist);
        scatter_kernel<<<blocks1, 256, 0, stream>>>(x, hist, sx, perm, N);
        px = sx;
        pperm = perm;
    }

    hash_level_kernel<<<blocks1, 256, 0, stream>>>(px, gtab + 299008u,
                                                   feat + (size_t)0 * N, 127.0f, N);
    hash_level_kernel<<<blocks1, 256, 0, stream>>>(px, gtab + 823296u,
                                                   feat + (size_t)1 * N, 255.0f, N);
    hash_level_kernel<<<blocks1, 256, 0, stream>>>(px, gtab + 1347584u,
                                                   feat + (size_t)2 * N, 511.0f, N);
    dense_mlp_kernel<<<blocks4, 256, 0, stream>>>(px, grid, feat, wt, pperm,
                                                  out, N);
}

// Round 10
// 335.064 us; speedup vs baseline: 1.7880x; 1.7880x over previous
//
#include <hip/hip_runtime.h>

// GridManifoldNetwork, round 10.
// R9: sort scrapped (scatter alone 206us: random 12B scatters write-allocate
// 64B HBM lines, 216MB WRITE_SIZE; downstream gain ~0). Standing model:
// random-gather wall ~0.237M 64B-lines/us chip-wide; hash levels (3x72us)
// are AT the wall and structural (sc0/merge/ILP/sort all neutral).
// R10 lever: dense_mlp's level-0+1 tables (16KB+128KB as packed bf16x2)
// fit gfx950's 160KB LDS -> move ~15M line-requests from TCP to the DS
// pipe. dense_mlp floor becomes level-2-only (~16.8M lines ~ 75-90us).
// >64KB dynamic LDS is gated via hipFuncGetAttributes (host-side,
// capture-safe, deterministic) with a 16KB level-0-only fallback.
//
// Levels: res=16,32,64,128,256,512; F=2; T=2^19; levels 3..5 hashed,
// size 2^19 -> & 0x7FFFF. Entry offsets: 0,4096,36864,299008,823296,1347584.
// Levels 0+1 are grid entries [0,36864) -- contiguous.

#define HP1 2654435761u
#define HP2 805459861u
#define HMASK ((1u << 19) - 1u)

static __device__ __forceinline__ unsigned umin_(unsigned a, unsigned b) {
    return a < b ? a : b;
}

// bf16 round-to-nearest-even pack/unpack.
static __device__ __forceinline__ unsigned f2bf(float f) {
    unsigned u = __float_as_uint(f);
    return (u + 0x7fffu + ((u >> 16) & 1u)) >> 16;
}
static __device__ __forceinline__ float bf2f_lo(unsigned p) {
    return __uint_as_float((p & 0xffffu) << 16);
}
static __device__ __forceinline__ float bf2f_hi(unsigned p) {
    return __uint_as_float(p & 0xffff0000u);
}

// Prep (64 blocks): packed[t] = bf16x2 of grid entry t for t in [0,36864)
// (levels 0+1); block 0 additionally builds wt[]: wt[j*16+i]=W0[i*64+j]
// (i=15 -> b0[j]), wt[1024+j]=W1[j], wt[1088]=b1.
__global__ __launch_bounds__(256) void prep_kernel(
    const float* __restrict__ W0, const float* __restrict__ b0,
    const float* __restrict__ W1, const float* __restrict__ b1,
    const float2* __restrict__ gtab,
    float* __restrict__ wt, unsigned* __restrict__ packed)
{
    for (int t = blockIdx.x * 256 + threadIdx.x; t < 36864;
         t += gridDim.x * 256) {
        const float2 e = gtab[t];
        packed[t] = f2bf(e.x) | (f2bf(e.y) << 16);
    }
    if (blockIdx.x == 0) {
        for (int t = threadIdx.x; t < 1024; t += 256) {
            const int j = t >> 4, i = t & 15;
            wt[t] = (i == 15) ? b0[j] : W0[i * 64 + j];
        }
        if (threadIdx.x < 64) wt[1024 + threadIdx.x] = W1[threadIdx.x];
        if (threadIdx.x == 0) wt[1088] = b1[0];
    }
}

// One hashed level: 8 divergent 8B gathers from a 4MB L2-resident table.
// At the random-line wall (~71us) -- declared structural.
__global__ __launch_bounds__(256) void hash_level_kernel(
    const float* __restrict__ x,
    const float2* __restrict__ tab,
    unsigned* __restrict__ feat,      // packed bf16x2 per point
    float scale, int N)
{
    const int gid = blockIdx.x * 256 + threadIdx.x;
    if (gid >= N) return;

    const float px = __builtin_nontemporal_load(x + 3 * gid + 0);
    const float py = __builtin_nontemporal_load(x + 3 * gid + 1);
    const float pz = __builtin_nontemporal_load(x + 3 * gid + 2);

    const float p0 = fmaf((px + 1.0f) * 0.5f, scale, 0.5f);
    const float p1 = fmaf((py + 1.0f) * 0.5f, scale, 0.5f);
    const float p2 = fmaf((pz + 1.0f) * 0.5f, scale, 0.5f);
    const float g0 = floorf(p0), g1 = floorf(p1), g2 = floorf(p2);
    const float f0 = p0 - g0, f1 = p1 - g1, f2 = p2 - g2;
    const unsigned i0 = (unsigned)g0, i1 = (unsigned)g1, i2 = (unsigned)g2;

    const float wx[2] = {1.0f - f0, f0};
    const float wy[2] = {1.0f - f1, f1};
    const float wz[2] = {1.0f - f2, f2};
    const unsigned hx[2] = {i0, i0 + 1u};
    const unsigned hy[2] = {i1 * HP1, (i1 + 1u) * HP1};
    const unsigned hz[2] = {i2 * HP2, (i2 + 1u) * HP2};

    unsigned idx[8];
    float w[8];
    #pragma unroll
    for (int c = 0; c < 8; ++c) {
        const int bx = c & 1, by = (c >> 1) & 1, bz = (c >> 2) & 1;
        idx[c] = (hx[bx] ^ hy[by] ^ hz[bz]) & HMASK;
        w[c] = wx[bx] * wy[by] * wz[bz];
    }
    float2 v[8];
    #pragma unroll
    for (int c = 0; c < 8; ++c) v[c] = tab[idx[c]];

    float a0 = 0.0f, a1 = 0.0f;
    #pragma unroll
    for (int c = 0; c < 8; ++c) {
        a0 = fmaf(w[c], v[c].x, a0);
        a1 = fmaf(w[c], v[c].y, a1);
    }
    __builtin_nontemporal_store(f2bf(a0) | (f2bf(a1) << 16), feat + gid);
}

// Dense trilinear level from global fp32 float2.
static __device__ __forceinline__ void dense_level(
    const float2* __restrict__ tab, unsigned res,
    float xn0, float xn1, float xn2, float& o0, float& o1)
{
    const float scale = (float)(res - 1);
    const float p0 = fmaf(xn0, scale, 0.5f);
    const float p1 = fmaf(xn1, scale, 0.5f);
    const float p2 = fmaf(xn2, scale, 0.5f);
    const float g0 = floorf(p0), g1 = floorf(p1), g2 = floorf(p2);
    const float f0 = p0 - g0, f1 = p1 - g1, f2 = p2 - g2;
    const unsigned i0 = (unsigned)g0, i1 = (unsigned)g1, i2 = (unsigned)g2;

    const unsigned rm1 = res - 1u;
    const unsigned cx[2] = {umin_(i0, rm1), umin_(i0 + 1u, rm1)};
    const unsigned cy[2] = {umin_(i1, rm1) * res, umin_(i1 + 1u, rm1) * res};
    const unsigned cz[2] = {umin_(i2, rm1) * res * res,
                            umin_(i2 + 1u, rm1) * res * res};
    const float wx[2] = {1.0f - f0, f0};
    const float wy[2] = {1.0f - f1, f1};
    const float wz[2] = {1.0f - f2, f2};

    float a0 = 0.0f, a1 = 0.0f;
    #pragma unroll
    for (int c = 0; c < 8; ++c) {
        const int bx = c & 1, by = (c >> 1) & 1, bz = (c >> 2) & 1;
        const unsigned idx = cx[bx] + cy[by] + cz[bz];
        const float w = wx[bx] * wy[by] * wz[bz];
        const float2 v = tab[idx];
        a0 = fmaf(w, v.x, a0);
        a1 = fmaf(w, v.y, a1);
    }
    o0 = a0;
    o1 = a1;
}

// Dense trilinear level from LDS-resident packed bf16x2 table.
static __device__ __forceinline__ void dense_level_lds(
    const unsigned* __restrict__ sPk, unsigned off, unsigned res,
    float xn0, float xn1, float xn2, float& o0, float& o1)
{
    const float scale = (float)(res - 1);
    const float p0 = fmaf(xn0, scale, 0.5f);
    const float p1 = fmaf(xn1, scale, 0.5f);
    const float p2 = fmaf(xn2, scale, 0.5f);
    const float g0 = floorf(p0), g1 = floorf(p1), g2 = floorf(p2);
    const float f0 = p0 - g0, f1 = p1 - g1, f2 = p2 - g2;
    const unsigned i0 = (unsigned)g0, i1 = (unsigned)g1, i2 = (unsigned)g2;

    const unsigned rm1 = res - 1u;
    const unsigned cx[2] = {umin_(i0, rm1), umin_(i0 + 1u, rm1)};
    const unsigned cy[2] = {umin_(i1, rm1) * res, umin_(i1 + 1u, rm1) * res};
    const unsigned cz[2] = {umin_(i2, rm1) * res * res,
                            umin_(i2 + 1u, rm1) * res * res};
    const float wx[2] = {1.0f - f0, f0};
    const float wy[2] = {1.0f - f1, f1};
    const float wz[2] = {1.0f - f2, f2};

    float a0 = 0.0f, a1 = 0.0f;
    #pragma unroll
    for (int c = 0; c < 8; ++c) {
        const int bx = c & 1, by = (c >> 1) & 1, bz = (c >> 2) & 1;
        const unsigned p = sPk[off + cx[bx] + cy[by] + cz[bz]];
        const float w = wx[bx] * wy[by] * wz[bz];
        a0 = fmaf(w, bf2f_lo(p), a0);
        a1 = fmaf(w, bf2f_hi(p), a1);
    }
    o0 = a0;
    o1 = a1;
}

// Dense levels + MLP, 4 points/thread. L1LDS=true: levels 0+1 from a 144KB
// LDS copy (DS pipe, off the TCP wall); false: level 0 only (16KB LDS).
// Level 2 always via TCP (2MB). Weights via SMEM pipe (s_load of wt rows).
template<int BLOCK, bool L1LDS>
__global__ __launch_bounds__(BLOCK, 4) void dense_mlp_kernel(
    const float* __restrict__ x,
    const float* __restrict__ grid,
    const unsigned* __restrict__ feat,   // [3][N] packed bf16x2
    const float* __restrict__ wt,        // 1089 floats
    const unsigned* __restrict__ packed, // 36864 bf16x2 words (levels 0+1)
    float* __restrict__ out, int N)
{
    extern __shared__ unsigned sPk[];
    const int tid = threadIdx.x;

    const int nstage = L1LDS ? 36864 : 4096;
    for (int t = tid; t < nstage; t += BLOCK)
        sPk[t] = packed[t];
    __syncthreads();

    const int base = blockIdx.x * (BLOCK * 4) + tid;
    const float2* gtab = (const float2*)grid;

    float h[4][16];

    #pragma unroll
    for (int k = 0; k < 4; ++k) {
        const int g = base + BLOCK * k;
        const int gs = (g < N) ? g : 0;

        const float px = __builtin_nontemporal_load(x + 3 * gs + 0);
        const float py = __builtin_nontemporal_load(x + 3 * gs + 1);
        const float pz = __builtin_nontemporal_load(x + 3 * gs + 2);
        const float xn0 = (px + 1.0f) * 0.5f;
        const float xn1 = (py + 1.0f) * 0.5f;
        const float xn2 = (pz + 1.0f) * 0.5f;

        h[k][0] = px; h[k][1] = py; h[k][2] = pz;
        h[k][15] = 1.0f;

        dense_level_lds(sPk, 0u, 16u, xn0, xn1, xn2, h[k][3], h[k][4]);
        if (L1LDS)
            dense_level_lds(sPk, 4096u, 32u, xn0, xn1, xn2, h[k][5], h[k][6]);
        else
            dense_level(gtab + 4096u, 32u, xn0, xn1, xn2, h[k][5], h[k][6]);
        dense_level(gtab + 36864u, 64u, xn0, xn1, xn2, h[k][7], h[k][8]);

        #pragma unroll
        for (int l = 0; l < 3; ++l) {
            const unsigned p = __builtin_nontemporal_load(
                feat + (size_t)l * N + gs);
            h[k][9 + 2 * l]  = bf2f_lo(p);
            h[k][10 + 2 * l] = bf2f_hi(p);
        }
    }

    // MLP: out = relu(h @ W0 + b0) @ W1 + b1 (bias folded via h[15]=1).
    const float b1v = wt[1088];
    float o[4] = {b1v, b1v, b1v, b1v};

    #pragma unroll 4
    for (int j = 0; j < 64; ++j) {
        float r[16];
        #pragma unroll
        for (int i = 0; i < 16; ++i)
            r[i] = wt[j * 16 + i];          // uniform -> s_load (SMEM pipe)
        const float w1j = wt[1024 + j];
        #pragma unroll
        for (int k = 0; k < 4; ++k) {
            float s = 0.0f;
            #pragma unroll
            for (int i = 0; i < 16; ++i)
                s = fmaf(h[k][i], r[i], s);  // v_fma with SGPR weight
            s = fmaxf(s, 0.0f);
            o[k] = fmaf(s, w1j, o[k]);
        }
    }

    #pragma unroll
    for (int k = 0; k < 4; ++k) {
        const int g = base + BLOCK * k;
        if (g < N) __builtin_nontemporal_store(o[k], out + g);
    }
}

extern "C" void kernel_launch(void* const* d_in, const int* in_sizes, int n_in,
                              void* d_out, int out_size, void* d_ws, size_t ws_size,
                              hipStream_t stream) {
    const float* x    = (const float*)d_in[0];
    const float* grid = (const float*)d_in[1];
    const float* W0   = (const float*)d_in[2];
    const float* b0   = (const float*)d_in[3];
    const float* W1   = (const float*)d_in[4];
    const float* b1   = (const float*)d_in[5];
    float* out = (float*)d_out;

    const int N = in_sizes[0] / 3;
    const int blocks1 = (N + 255) / 256;

    const float2* gtab = (const float2*)grid;

    auto align256 = [](size_t v) { return (v + 255) & ~(size_t)255; };
    size_t off = 0;
    const size_t feat_off = off; off += align256((size_t)3 * N * 4);
    const size_t wt_off   = off; off += align256(1089 * 4);
    const size_t pk_off   = off; off += align256(36864 * 4);
    (void)ws_size;

    unsigned* feat   = (unsigned*)((char*)d_ws + feat_off);
    float*    wt     = (float*)((char*)d_ws + wt_off);
    unsigned* packed = (unsigned*)((char*)d_ws + pk_off);

    prep_kernel<<<64, 256, 0, stream>>>(W0, b0, W1, b1, gtab, wt, packed);

    hash_level_kernel<<<blocks1, 256, 0, stream>>>(x, gtab + 299008u,
                                                   feat + (size_t)0 * N, 127.0f, N);
    hash_level_kernel<<<blocks1, 256, 0, stream>>>(x, gtab + 823296u,
                                                   feat + (size_t)1 * N, 255.0f, N);
    hash_level_kernel<<<blocks1, 256, 0, stream>>>(x, gtab + 1347584u,
                                                   feat + (size_t)2 * N, 511.0f, N);

    // Gate the 144KB-LDS path on what the runtime actually permits
    // (host-side queries: deterministic, graph-capture-safe).
    const size_t bigShm = 36864u * 4u;           // 147456 B
    const void* bigK =
        reinterpret_cast<const void*>(&dense_mlp_kernel<1024, true>);
    (void)hipFuncSetAttribute(bigK,
        hipFuncAttributeMaxDynamicSharedMemorySize, (int)bigShm);
    bool big = false;
    hipFuncAttributes fa{};
    if (hipFuncGetAttributes(&fa, bigK) == hipSuccess)
        big = ((size_t)fa.maxDynamicSharedSizeBytes >= bigShm);

    if (big) {
        const int blocksB = (N + 4095) / 4096;   // 1024 thr x 4 pts
        dense_mlp_kernel<1024, true><<<blocksB, 1024, bigShm, stream>>>(
            x, (const float*)grid, feat, wt, packed, out, N);
    } else {
        const int blocksF = (N + 1023) / 1024;   // 256 thr x 4 pts
        dense_mlp_kernel<256, false><<<blocksF, 256, 4096u * 4u, stream>>>(
            x, (const float*)grid, feat, wt, packed, out, N);
    }
}

// Round 11
// 318.615 us; speedup vs baseline: 1.8804x; 1.0516x over previous
//
#include <hip/hip_runtime.h>

// GridManifoldNetwork, round 11.
// R10: L0+L1 LDS staging WIN (128->112.5us, big-LDS 1024-thr path active).
// dense_mlp now VALU-bound (VALUBusy 68% = ~76us of 112): MLP is ~80% of
// per-point VALU (64x18 lane-FMAs). R11 lever: pack the MLP over 2-point
// float2 vectors so LLVM emits V_PK_FMA_F32 (CDNA3+ double-rate fp32,
// scalar weight broadcast from SGPR) -> halves MLP VALU issue. Same ops
// per point in same order -> absmax unchanged.
// Hash levels (3x72us) declared structural: sc0 / width-merge / ILP / sort
// all neutral; consistent with per-CU TCP outstanding-miss throughput cap.
//
// Levels: res=16,32,64,128,256,512; F=2; T=2^19; levels 3..5 hashed,
// size 2^19 -> & 0x7FFFF. Entry offsets: 0,4096,36864,299008,823296,1347584.
// Levels 0+1 are grid entries [0,36864) -- contiguous, staged to LDS as
// packed bf16x2 (144KB).

#define HP1 2654435761u
#define HP2 805459861u
#define HMASK ((1u << 19) - 1u)

typedef float v2f __attribute__((ext_vector_type(2)));

static __device__ __forceinline__ unsigned umin_(unsigned a, unsigned b) {
    return a < b ? a : b;
}

// bf16 round-to-nearest-even pack/unpack.
static __device__ __forceinline__ unsigned f2bf(float f) {
    unsigned u = __float_as_uint(f);
    return (u + 0x7fffu + ((u >> 16) & 1u)) >> 16;
}
static __device__ __forceinline__ float bf2f_lo(unsigned p) {
    return __uint_as_float((p & 0xffffu) << 16);
}
static __device__ __forceinline__ float bf2f_hi(unsigned p) {
    return __uint_as_float(p & 0xffff0000u);
}

static __device__ __forceinline__ v2f vmax0(v2f s) {
#if __has_builtin(__builtin_elementwise_max)
    return __builtin_elementwise_max(s, (v2f)0.0f);
#else
    v2f r; r.x = fmaxf(s.x, 0.0f); r.y = fmaxf(s.y, 0.0f); return r;
#endif
}

// Prep (64 blocks): packed[t] = bf16x2 of grid entry t for t in [0,36864)
// (levels 0+1); block 0 additionally builds wt[]: wt[j*16+i]=W0[i*64+j]
// (i=15 -> b0[j]), wt[1024+j]=W1[j], wt[1088]=b1.
__global__ __launch_bounds__(256) void prep_kernel(
    const float* __restrict__ W0, const float* __restrict__ b0,
    const float* __restrict__ W1, const float* __restrict__ b1,
    const float2* __restrict__ gtab,
    float* __restrict__ wt, unsigned* __restrict__ packed)
{
    for (int t = blockIdx.x * 256 + threadIdx.x; t < 36864;
         t += gridDim.x * 256) {
        const float2 e = gtab[t];
        packed[t] = f2bf(e.x) | (f2bf(e.y) << 16);
    }
    if (blockIdx.x == 0) {
        for (int t = threadIdx.x; t < 1024; t += 256) {
            const int j = t >> 4, i = t & 15;
            wt[t] = (i == 15) ? b0[j] : W0[i * 64 + j];
        }
        if (threadIdx.x < 64) wt[1024 + threadIdx.x] = W1[threadIdx.x];
        if (threadIdx.x == 0) wt[1088] = b1[0];
    }
}

// One hashed level: 8 divergent 8B gathers from a 4MB L2-resident table.
// At the random-gather wall (~71us) -- structural.
__global__ __launch_bounds__(256) void hash_level_kernel(
    const float* __restrict__ x,
    const float2* __restrict__ tab,
    unsigned* __restrict__ feat,      // packed bf16x2 per point
    float scale, int N)
{
    const int gid = blockIdx.x * 256 + threadIdx.x;
    if (gid >= N) return;

    const float px = __builtin_nontemporal_load(x + 3 * gid + 0);
    const float py = __builtin_nontemporal_load(x + 3 * gid + 1);
    const float pz = __builtin_nontemporal_load(x + 3 * gid + 2);

    const float p0 = fmaf((px + 1.0f) * 0.5f, scale, 0.5f);
    const float p1 = fmaf((py + 1.0f) * 0.5f, scale, 0.5f);
    const float p2 = fmaf((pz + 1.0f) * 0.5f, scale, 0.5f);
    const float g0 = floorf(p0), g1 = floorf(p1), g2 = floorf(p2);
    const float f0 = p0 - g0, f1 = p1 - g1, f2 = p2 - g2;
    const unsigned i0 = (unsigned)g0, i1 = (unsigned)g1, i2 = (unsigned)g2;

    const float wx[2] = {1.0f - f0, f0};
    const float wy[2] = {1.0f - f1, f1};
    const float wz[2] = {1.0f - f2, f2};
    const unsigned hx[2] = {i0, i0 + 1u};
    const unsigned hy[2] = {i1 * HP1, (i1 + 1u) * HP1};
    const unsigned hz[2] = {i2 * HP2, (i2 + 1u) * HP2};

    unsigned idx[8];
    float w[8];
    #pragma unroll
    for (int c = 0; c < 8; ++c) {
        const int bx = c & 1, by = (c >> 1) & 1, bz = (c >> 2) & 1;
        idx[c] = (hx[bx] ^ hy[by] ^ hz[bz]) & HMASK;
        w[c] = wx[bx] * wy[by] * wz[bz];
    }
    float2 v[8];
    #pragma unroll
    for (int c = 0; c < 8; ++c) v[c] = tab[idx[c]];

    float a0 = 0.0f, a1 = 0.0f;
    #pragma unroll
    for (int c = 0; c < 8; ++c) {
        a0 = fmaf(w[c], v[c].x, a0);
        a1 = fmaf(w[c], v[c].y, a1);
    }
    __builtin_nontemporal_store(f2bf(a0) | (f2bf(a1) << 16), feat + gid);
}

// Dense trilinear level from global fp32 float2 (level 2).
static __device__ __forceinline__ void dense_level(
    const float2* __restrict__ tab, unsigned res,
    float xn0, float xn1, float xn2, float& o0, float& o1)
{
    const float scale = (float)(res - 1);
    const float p0 = fmaf(xn0, scale, 0.5f);
    const float p1 = fmaf(xn1, scale, 0.5f);
    const float p2 = fmaf(xn2, scale, 0.5f);
    const float g0 = floorf(p0), g1 = floorf(p1), g2 = floorf(p2);
    const float f0 = p0 - g0, f1 = p1 - g1, f2 = p2 - g2;
    const unsigned i0 = (unsigned)g0, i1 = (unsigned)g1, i2 = (unsigned)g2;

    const unsigned rm1 = res - 1u;
    const unsigned cx[2] = {umin_(i0, rm1), umin_(i0 + 1u, rm1)};
    const unsigned cy[2] = {umin_(i1, rm1) * res, umin_(i1 + 1u, rm1) * res};
    const unsigned cz[2] = {umin_(i2, rm1) * res * res,
                            umin_(i2 + 1u, rm1) * res * res};
    const float wx[2] = {1.0f - f0, f0};
    const float wy[2] = {1.0f - f1, f1};
    const float wz[2] = {1.0f - f2, f2};

    float a0 = 0.0f, a1 = 0.0f;
    #pragma unroll
    for (int c = 0; c < 8; ++c) {
        const int bx = c & 1, by = (c >> 1) & 1, bz = (c >> 2) & 1;
        const unsigned idx = cx[bx] + cy[by] + cz[bz];
        const float w = wx[bx] * wy[by] * wz[bz];
        const float2 v = tab[idx];
        a0 = fmaf(w, v.x, a0);
        a1 = fmaf(w, v.y, a1);
    }
    o0 = a0;
    o1 = a1;
}

// Dense trilinear level from LDS-resident packed bf16x2 table.
static __device__ __forceinline__ void dense_level_lds(
    const unsigned* __restrict__ sPk, unsigned off, unsigned res,
    float xn0, float xn1, float xn2, float& o0, float& o1)
{
    const float scale = (float)(res - 1);
    const float p0 = fmaf(xn0, scale, 0.5f);
    const float p1 = fmaf(xn1, scale, 0.5f);
    const float p2 = fmaf(xn2, scale, 0.5f);
    const float g0 = floorf(p0), g1 = floorf(p1), g2 = floorf(p2);
    const float f0 = p0 - g0, f1 = p1 - g1, f2 = p2 - g2;
    const unsigned i0 = (unsigned)g0, i1 = (unsigned)g1, i2 = (unsigned)g2;

    const unsigned rm1 = res - 1u;
    const unsigned cx[2] = {umin_(i0, rm1), umin_(i0 + 1u, rm1)};
    const unsigned cy[2] = {umin_(i1, rm1) * res, umin_(i1 + 1u, rm1) * res};
    const unsigned cz[2] = {umin_(i2, rm1) * res * res,
                            umin_(i2 + 1u, rm1) * res * res};
    const float wx[2] = {1.0f - f0, f0};
    const float wy[2] = {1.0f - f1, f1};
    const float wz[2] = {1.0f - f2, f2};

    float a0 = 0.0f, a1 = 0.0f;
    #pragma unroll
    for (int c = 0; c < 8; ++c) {
        const int bx = c & 1, by = (c >> 1) & 1, bz = (c >> 2) & 1;
        const unsigned p = sPk[off + cx[bx] + cy[by] + cz[bz]];
        const float w = wx[bx] * wy[by] * wz[bz];
        a0 = fmaf(w, bf2f_lo(p), a0);
        a1 = fmaf(w, bf2f_hi(p), a1);
    }
    o0 = a0;
    o1 = a1;
}

// Dense levels + MLP, 4 points/thread. L1LDS=true: levels 0+1 from a 144KB
// LDS copy; false: level 0 only (16KB). Level 2 always via TCP. Weights via
// SMEM pipe. MLP computed over 2-point float2 pairs -> v_pk_fma_f32.
template<int BLOCK, bool L1LDS>
__global__ __launch_bounds__(BLOCK, 4) void dense_mlp_kernel(
    const float* __restrict__ x,
    const float* __restrict__ grid,
    const unsigned* __restrict__ feat,   // [3][N] packed bf16x2
    const float* __restrict__ wt,        // 1089 floats
    const unsigned* __restrict__ packed, // 36864 bf16x2 words (levels 0+1)
    float* __restrict__ out, int N)
{
    extern __shared__ unsigned sPk[];
    const int tid = threadIdx.x;

    const int nstage = L1LDS ? 36864 : 4096;
    for (int t = tid; t < nstage; t += BLOCK)
        sPk[t] = packed[t];
    __syncthreads();

    const int base = blockIdx.x * (BLOCK * 4) + tid;
    const float2* gtab = (const float2*)grid;

    // hp[p][i] = {feature i of point 2p, feature i of point 2p+1}
    v2f hp[2][16];

    #pragma unroll
    for (int k = 0; k < 4; ++k) {
        const int g = base + BLOCK * k;
        const int gs = (g < N) ? g : 0;
        const int p = k >> 1, lane = k & 1;

        const float px = __builtin_nontemporal_load(x + 3 * gs + 0);
        const float py = __builtin_nontemporal_load(x + 3 * gs + 1);
        const float pz = __builtin_nontemporal_load(x + 3 * gs + 2);
        const float xn0 = (px + 1.0f) * 0.5f;
        const float xn1 = (py + 1.0f) * 0.5f;
        const float xn2 = (pz + 1.0f) * 0.5f;

        hp[p][0][lane] = px; hp[p][1][lane] = py; hp[p][2][lane] = pz;
        hp[p][15][lane] = 1.0f;

        float t3, t4, t5, t6, t7, t8;
        dense_level_lds(sPk, 0u, 16u, xn0, xn1, xn2, t3, t4);
        if (L1LDS)
            dense_level_lds(sPk, 4096u, 32u, xn0, xn1, xn2, t5, t6);
        else
            dense_level(gtab + 4096u, 32u, xn0, xn1, xn2, t5, t6);
        dense_level(gtab + 36864u, 64u, xn0, xn1, xn2, t7, t8);
        hp[p][3][lane] = t3; hp[p][4][lane] = t4;
        hp[p][5][lane] = t5; hp[p][6][lane] = t6;
        hp[p][7][lane] = t7; hp[p][8][lane] = t8;

        #pragma unroll
        for (int l = 0; l < 3; ++l) {
            const unsigned pk = __builtin_nontemporal_load(
                feat + (size_t)l * N + gs);
            hp[p][9 + 2 * l][lane]  = bf2f_lo(pk);
            hp[p][10 + 2 * l][lane] = bf2f_hi(pk);
        }
    }

    // MLP: out = relu(h @ W0 + b0) @ W1 + b1 (bias folded via h[15]=1).
    // 2-pt float2 vectors, scalar weights (SGPR broadcast) -> v_pk_fma_f32.
    const float b1v = wt[1088];
    v2f o2[2];
    o2[0] = (v2f)b1v; o2[1] = (v2f)b1v;

    #pragma unroll 4
    for (int j = 0; j < 64; ++j) {
        float r[16];
        #pragma unroll
        for (int i = 0; i < 16; ++i)
            r[i] = wt[j * 16 + i];          // uniform -> s_load (SMEM pipe)
        const float w1j = wt[1024 + j];
        #pragma unroll
        for (int p = 0; p < 2; ++p) {
            v2f s = (v2f)0.0f;
            #pragma unroll
            for (int i = 0; i < 16; ++i)
                s = hp[p][i] * r[i] + s;     // contracts to packed fma
            s = vmax0(s);
            o2[p] = s * w1j + o2[p];
        }
    }

    #pragma unroll
    for (int k = 0; k < 4; ++k) {
        const int g = base + BLOCK * k;
        if (g < N)
            __builtin_nontemporal_store(o2[k >> 1][k & 1], out + g);
    }
}

extern "C" void kernel_launch(void* const* d_in, const int* in_sizes, int n_in,
                              void* d_out, int out_size, void* d_ws, size_t ws_size,
                              hipStream_t stream) {
    const float* x    = (const float*)d_in[0];
    const float* grid = (const float*)d_in[1];
    const float* W0   = (const float*)d_in[2];
    const float* b0   = (const float*)d_in[3];
    const float* W1   = (const float*)d_in[4];
    const float* b1   = (const float*)d_in[5];
    float* out = (float*)d_out;

    const int N = in_sizes[0] / 3;
    const int blocks1 = (N + 255) / 256;

    const float2* gtab = (const float2*)grid;

    auto align256 = [](size_t v) { return (v + 255) & ~(size_t)255; };
    size_t off = 0;
    const size_t feat_off = off; off += align256((size_t)3 * N * 4);
    const size_t wt_off   = off; off += align256(1089 * 4);
    const size_t pk_off   = off; off += align256(36864 * 4);
    (void)ws_size;

    unsigned* feat   = (unsigned*)((char*)d_ws + feat_off);
    float*    wt     = (float*)((char*)d_ws + wt_off);
    unsigned* packed = (unsigned*)((char*)d_ws + pk_off);

    prep_kernel<<<64, 256, 0, stream>>>(W0, b0, W1, b1, gtab, wt, packed);

    hash_level_kernel<<<blocks1, 256, 0, stream>>>(x, gtab + 299008u,
                                                   feat + (size_t)0 * N, 127.0f, N);
    hash_level_kernel<<<blocks1, 256, 0, stream>>>(x, gtab + 823296u,
                                                   feat + (size_t)1 * N, 255.0f, N);
    hash_level_kernel<<<blocks1, 256, 0, stream>>>(x, gtab + 1347584u,
                                                   feat + (size_t)2 * N, 511.0f, N);

    // Gate the 144KB-LDS path on what the runtime actually permits
    // (host-side queries: deterministic, graph-capture-safe).
    const size_t bigShm = 36864u * 4u;           // 147456 B
    const void* bigK =
        reinterpret_cast<const void*>(&dense_mlp_kernel<1024, true>);
    (void)hipFuncSetAttribute(bigK,
        hipFuncAttributeMaxDynamicSharedMemorySize, (int)bigShm);
    bool big = false;
    hipFuncAttributes fa{};
    if (hipFuncGetAttributes(&fa, bigK) == hipSuccess)
        big = ((size_t)fa.maxDynamicSharedSizeBytes >= bigShm);

    if (big) {
        const int blocksB = (N + 4095) / 4096;   // 1024 thr x 4 pts
        dense_mlp_kernel<1024, true><<<blocksB, 1024, bigShm, stream>>>(
            x, (const float*)grid, feat, wt, packed, out, N);
    } else {
        const int blocksF = (N + 1023) / 1024;   // 256 thr x 4 pts
        dense_mlp_kernel<256, false><<<blocksF, 256, 4096u * 4u, stream>>>(
            x, (const float*)grid, feat, wt, packed, out, N);
    }
}

// Round 12
// 318.358 us; speedup vs baseline: 1.8819x; 1.0008x over previous
//
#include <hip/hip_runtime.h>

// GridManifoldNetwork, round 12.
// R11: packed-fp32 MLP WIN (112.5->94.9us, VALUBusy 68->51%). Standing:
// hash levels 3x72.5us at the random-64B-line wall (~0.233M lines/us chip;
// sc0/merge/ILP/sort all falsified) -- structural. dense_mlp ideal =
// max(VALU 48, L2-lines ~38) ~= 55-65us but runs 94.9: per-corner
// addr->load->fma chains serialize gather latency (VGPR 48 = no hoisting).
// R12: (1) dense_mlp batches all level-2+feat loads per 2-pt half BEFORE
// the L0/L1 LDS lerps (latency hidden under DS/VALU work; v2f-packed
// lerps); (2) prep folded into hash-level-3 kernel's tail blocks.
//
// Levels: res=16,32,64,128,256,512; F=2; T=2^19; levels 3..5 hashed,
// size 2^19 -> & 0x7FFFF. Entry offsets: 0,4096,36864,299008,823296,1347584.
// Levels 0+1 (entries [0,36864)) staged to LDS as packed bf16x2 (144KB).

#define HP1 2654435761u
#define HP2 805459861u
#define HMASK ((1u << 19) - 1u)

typedef float v2f __attribute__((ext_vector_type(2)));

static __device__ __forceinline__ unsigned umin_(unsigned a, unsigned b) {
    return a < b ? a : b;
}

// bf16 round-to-nearest-even pack/unpack.
static __device__ __forceinline__ unsigned f2bf(float f) {
    unsigned u = __float_as_uint(f);
    return (u + 0x7fffu + ((u >> 16) & 1u)) >> 16;
}
static __device__ __forceinline__ float bf2f_lo(unsigned p) {
    return __uint_as_float((p & 0xffffu) << 16);
}
static __device__ __forceinline__ float bf2f_hi(unsigned p) {
    return __uint_as_float(p & 0xffff0000u);
}

static __device__ __forceinline__ v2f vmax0(v2f s) {
#if __has_builtin(__builtin_elementwise_max)
    return __builtin_elementwise_max(s, (v2f)0.0f);
#else
    v2f r; r.x = fmaxf(s.x, 0.0f); r.y = fmaxf(s.y, 0.0f); return r;
#endif
}

// One hashed-level point block: 8 divergent 8B gathers + trilerp + bf16 pack.
static __device__ __forceinline__ void hash_body(
    const float* __restrict__ x, const float2* __restrict__ tab,
    unsigned* __restrict__ feat, float scale, int N, int bid)
{
    const int gid = bid * 256 + threadIdx.x;
    if (gid >= N) return;

    const float px = __builtin_nontemporal_load(x + 3 * gid + 0);
    const float py = __builtin_nontemporal_load(x + 3 * gid + 1);
    const float pz = __builtin_nontemporal_load(x + 3 * gid + 2);

    const float p0 = fmaf((px + 1.0f) * 0.5f, scale, 0.5f);
    const float p1 = fmaf((py + 1.0f) * 0.5f, scale, 0.5f);
    const float p2 = fmaf((pz + 1.0f) * 0.5f, scale, 0.5f);
    const float g0 = floorf(p0), g1 = floorf(p1), g2 = floorf(p2);
    const float f0 = p0 - g0, f1 = p1 - g1, f2 = p2 - g2;
    const unsigned i0 = (unsigned)g0, i1 = (unsigned)g1, i2 = (unsigned)g2;

    const float wx[2] = {1.0f - f0, f0};
    const float wy[2] = {1.0f - f1, f1};
    const float wz[2] = {1.0f - f2, f2};
    const unsigned hx[2] = {i0, i0 + 1u};
    const unsigned hy[2] = {i1 * HP1, (i1 + 1u) * HP1};
    const unsigned hz[2] = {i2 * HP2, (i2 + 1u) * HP2};

    unsigned idx[8];
    float w[8];
    #pragma unroll
    for (int c = 0; c < 8; ++c) {
        const int bx = c & 1, by = (c >> 1) & 1, bz = (c >> 2) & 1;
        idx[c] = (hx[bx] ^ hy[by] ^ hz[bz]) & HMASK;
        w[c] = wx[bx] * wy[by] * wz[bz];
    }
    float2 v[8];
    #pragma unroll
    for (int c = 0; c < 8; ++c) v[c] = tab[idx[c]];

    float a0 = 0.0f, a1 = 0.0f;
    #pragma unroll
    for (int c = 0; c < 8; ++c) {
        a0 = fmaf(w[c], v[c].x, a0);
        a1 = fmaf(w[c], v[c].y, a1);
    }
    __builtin_nontemporal_store(f2bf(a0) | (f2bf(a1) << 16), feat + gid);
}

// Hash level 3 + prep folded into 64 tail blocks (absorbed in kernel tail;
// wt/packed ready before dense_mlp by stream order).
__global__ __launch_bounds__(256) void hash3_prep_kernel(
    const float* __restrict__ x, const float2* __restrict__ gtab,
    unsigned* __restrict__ feat0, int N,
    float* __restrict__ wt, unsigned* __restrict__ packed,
    const float* __restrict__ W0, const float* __restrict__ b0,
    const float* __restrict__ W1, const float* __restrict__ b1)
{
    const int nh = (int)gridDim.x - 64;
    if ((int)blockIdx.x >= nh) {
        const int pb = (int)blockIdx.x - nh;   // 0..63
        for (int t = pb * 256 + threadIdx.x; t < 36864; t += 64 * 256) {
            const float2 e = gtab[t];
            packed[t] = f2bf(e.x) | (f2bf(e.y) << 16);
        }
        if (pb == 0) {
            for (int t = threadIdx.x; t < 1024; t += 256) {
                const int j = t >> 4, i = t & 15;
                wt[t] = (i == 15) ? b0[j] : W0[i * 64 + j];
            }
            if (threadIdx.x < 64) wt[1024 + threadIdx.x] = W1[threadIdx.x];
            if (threadIdx.x == 0) wt[1088] = b1[0];
        }
        return;
    }
    hash_body(x, gtab + 299008u, feat0, 127.0f, N, (int)blockIdx.x);
}

__global__ __launch_bounds__(256) void hash_level_kernel(
    const float* __restrict__ x, const float2* __restrict__ tab,
    unsigned* __restrict__ feat, float scale, int N)
{
    hash_body(x, tab, feat, scale, N, (int)blockIdx.x);
}

// Trilinear lerp from LDS-resident packed bf16x2 table, v2f accumulate.
static __device__ __forceinline__ v2f lds_lerp(
    const unsigned* __restrict__ sPk, unsigned off, unsigned res,
    float xn0, float xn1, float xn2)
{
    const float scale = (float)(res - 1);
    const float p0 = fmaf(xn0, scale, 0.5f);
    const float p1 = fmaf(xn1, scale, 0.5f);
    const float p2 = fmaf(xn2, scale, 0.5f);
    const float g0 = floorf(p0), g1 = floorf(p1), g2 = floorf(p2);
    const float f0 = p0 - g0, f1 = p1 - g1, f2 = p2 - g2;
    const unsigned i0 = (unsigned)g0, i1 = (unsigned)g1, i2 = (unsigned)g2;

    const unsigned rm1 = res - 1u;
    const unsigned cx[2] = {umin_(i0, rm1), umin_(i0 + 1u, rm1)};
    const unsigned cy[2] = {umin_(i1, rm1) * res, umin_(i1 + 1u, rm1) * res};
    const unsigned cz[2] = {umin_(i2, rm1) * res * res,
                            umin_(i2 + 1u, rm1) * res * res};
    const float wx[2] = {1.0f - f0, f0};
    const float wy[2] = {1.0f - f1, f1};
    const float wz[2] = {1.0f - f2, f2};

    v2f acc = (v2f)0.0f;
    #pragma unroll
    for (int c = 0; c < 8; ++c) {
        const int bx = c & 1, by = (c >> 1) & 1, bz = (c >> 2) & 1;
        const unsigned q = sPk[off + cx[bx] + cy[by] + cz[bz]];
        v2f uv;
        uv.x = __uint_as_float(q << 16);
        uv.y = __uint_as_float(q & 0xffff0000u);
        acc = uv * (wx[bx] * wy[by] * wz[bz]) + acc;   // v_pk_fma_f32
    }
    return acc;
}

// Fallback-path L1 lerp from global fp32 (only if 144KB LDS unavailable).
static __device__ __forceinline__ v2f global_lerp(
    const float2* __restrict__ tab, unsigned res,
    float xn0, float xn1, float xn2)
{
    const float scale = (float)(res - 1);
    const float p0 = fmaf(xn0, scale, 0.5f);
    const float p1 = fmaf(xn1, scale, 0.5f);
    const float p2 = fmaf(xn2, scale, 0.5f);
    const float g0 = floorf(p0), g1 = floorf(p1), g2 = floorf(p2);
    const float f0 = p0 - g0, f1 = p1 - g1, f2 = p2 - g2;
    const unsigned i0 = (unsigned)g0, i1 = (unsigned)g1, i2 = (unsigned)g2;

    const unsigned rm1 = res - 1u;
    const unsigned cx[2] = {umin_(i0, rm1), umin_(i0 + 1u, rm1)};
    const unsigned cy[2] = {umin_(i1, rm1) * res, umin_(i1 + 1u, rm1) * res};
    const unsigned cz[2] = {umin_(i2, rm1) * res * res,
                            umin_(i2 + 1u, rm1) * res * res};
    const float wx[2] = {1.0f - f0, f0};
    const float wy[2] = {1.0f - f1, f1};
    const float wz[2] = {1.0f - f2, f2};

    v2f acc = (v2f)0.0f;
    #pragma unroll
    for (int c = 0; c < 8; ++c) {
        const int bx = c & 1, by = (c >> 1) & 1, bz = (c >> 2) & 1;
        const float2 v = tab[cx[bx] + cy[by] + cz[bz]];
        v2f uv; uv.x = v.x; uv.y = v.y;
        acc = uv * (wx[bx] * wy[by] * wz[bz]) + acc;
    }
    return acc;
}

// Dense levels + MLP, 4 points/thread in 2-point halves. Per half: issue
// ALL level-2 + feat loads, then L0/L1 LDS lerps (hides global latency),
// then consume. Weights via SMEM pipe; MLP over 2-pt v2f (v_pk_fma_f32).
template<int BLOCK, bool L1LDS>
__global__ __launch_bounds__(BLOCK, 4) void dense_mlp_kernel(
    const float* __restrict__ x,
    const float* __restrict__ grid,
    const unsigned* __restrict__ feat,   // [3][N] packed bf16x2
    const float* __restrict__ wt,        // 1089 floats
    const unsigned* __restrict__ packed, // 36864 bf16x2 words (levels 0+1)
    float* __restrict__ out, int N)
{
    extern __shared__ unsigned sPk[];
    const int tid = threadIdx.x;

    const int nstage = L1LDS ? 36864 : 4096;
    for (int t = tid; t < nstage; t += BLOCK)
        sPk[t] = packed[t];
    __syncthreads();

    const int base = blockIdx.x * (BLOCK * 4) + tid;
    const float2* gtab = (const float2*)grid;
    const float2* tab2 = gtab + 36864u;   // level 2

    // hp[p][i] = {feature i of point 2p, feature i of point 2p+1}
    v2f hp[2][16];

    #pragma unroll
    for (int p = 0; p < 2; ++p) {
        float  xn[2][3];
        float  fr[2][3];
        float2 vg[2][8];
        unsigned fw[2][3];

        // Phase A: x loads, level-2 address calc, issue 16 gathers + 6 feat.
        #pragma unroll
        for (int e = 0; e < 2; ++e) {
            const int k = 2 * p + e;
            const int g = base + BLOCK * k;
            const int gs = (g < N) ? g : 0;

            const float px = __builtin_nontemporal_load(x + 3 * gs + 0);
            const float py = __builtin_nontemporal_load(x + 3 * gs + 1);
            const float pz = __builtin_nontemporal_load(x + 3 * gs + 2);
            hp[p][0][e] = px; hp[p][1][e] = py; hp[p][2][e] = pz;
            hp[p][15][e] = 1.0f;
            xn[e][0] = (px + 1.0f) * 0.5f;
            xn[e][1] = (py + 1.0f) * 0.5f;
            xn[e][2] = (pz + 1.0f) * 0.5f;

            // level-2 (res 64) addresses
            const float q0 = fmaf(xn[e][0], 63.0f, 0.5f);
            const float q1 = fmaf(xn[e][1], 63.0f, 0.5f);
            const float q2 = fmaf(xn[e][2], 63.0f, 0.5f);
            const float g0 = floorf(q0), g1 = floorf(q1), g2 = floorf(q2);
            fr[e][0] = q0 - g0; fr[e][1] = q1 - g1; fr[e][2] = q2 - g2;
            const unsigned i0 = (unsigned)g0, i1 = (unsigned)g1,
                           i2 = (unsigned)g2;
            const unsigned cx[2] = {umin_(i0, 63u), umin_(i0 + 1u, 63u)};
            const unsigned cy[2] = {umin_(i1, 63u) * 64u,
                                    umin_(i1 + 1u, 63u) * 64u};
            const unsigned cz[2] = {umin_(i2, 63u) * 4096u,
                                    umin_(i2 + 1u, 63u) * 4096u};
            #pragma unroll
            for (int c = 0; c < 8; ++c) {
                const int bx = c & 1, by = (c >> 1) & 1, bz = (c >> 2) & 1;
                vg[e][c] = tab2[cx[bx] + cy[by] + cz[bz]];
            }
            #pragma unroll
            for (int l = 0; l < 3; ++l)
                fw[e][l] = __builtin_nontemporal_load(
                    feat + (size_t)l * N + gs);
        }

        // Phase B: L0/L1 lerps on the DS pipe while globals are in flight.
        #pragma unroll
        for (int e = 0; e < 2; ++e) {
            const v2f l0 = lds_lerp(sPk, 0u, 16u,
                                    xn[e][0], xn[e][1], xn[e][2]);
            hp[p][3][e] = l0.x; hp[p][4][e] = l0.y;
            v2f l1;
            if (L1LDS)
                l1 = lds_lerp(sPk, 4096u, 32u,
                              xn[e][0], xn[e][1], xn[e][2]);
            else
                l1 = global_lerp(gtab + 4096u, 32u,
                                 xn[e][0], xn[e][1], xn[e][2]);
            hp[p][5][e] = l1.x; hp[p][6][e] = l1.y;
        }

        // Phase C: consume level-2 values + feat.
        #pragma unroll
        for (int e = 0; e < 2; ++e) {
            const float wx[2] = {1.0f - fr[e][0], fr[e][0]};
            const float wy[2] = {1.0f - fr[e][1], fr[e][1]};
            const float wz[2] = {1.0f - fr[e][2], fr[e][2]};
            float wyz[4];
            #pragma unroll
            for (int c = 0; c < 4; ++c)
                wyz[c] = wy[c & 1] * wz[c >> 1];
            v2f acc = (v2f)0.0f;
            #pragma unroll
            for (int c = 0; c < 8; ++c) {
                v2f uv; uv.x = vg[e][c].x; uv.y = vg[e][c].y;
                acc = uv * (wx[c & 1] * wyz[c >> 1]) + acc;   // pk_fma
            }
            hp[p][7][e] = acc.x; hp[p][8][e] = acc.y;

            #pragma unroll
            for (int l = 0; l < 3; ++l) {
                hp[p][9 + 2 * l][e]  = bf2f_lo(fw[e][l]);
                hp[p][10 + 2 * l][e] = bf2f_hi(fw[e][l]);
            }
        }
    }

    // MLP: out = relu(h @ W0 + b0) @ W1 + b1 (bias folded via h[15]=1).
    const float b1v = wt[1088];
    v2f o2[2];
    o2[0] = (v2f)b1v; o2[1] = (v2f)b1v;

    #pragma unroll 4
    for (int j = 0; j < 64; ++j) {
        float r[16];
        #pragma unroll
        for (int i = 0; i < 16; ++i)
            r[i] = wt[j * 16 + i];          // uniform -> s_load (SMEM pipe)
        const float w1j = wt[1024 + j];
        #pragma unroll
        for (int p = 0; p < 2; ++p) {
            v2f s = (v2f)0.0f;
            #pragma unroll
            for (int i = 0; i < 16; ++i)
                s = hp[p][i] * r[i] + s;     // v_pk_fma_f32
            s = vmax0(s);
            o2[p] = s * w1j + o2[p];
        }
    }

    #pragma unroll
    for (int k = 0; k < 4; ++k) {
        const int g = base + BLOCK * k;
        if (g < N)
            __builtin_nontemporal_store(o2[k >> 1][k & 1], out + g);
    }
}

extern "C" void kernel_launch(void* const* d_in, const int* in_sizes, int n_in,
                              void* d_out, int out_size, void* d_ws, size_t ws_size,
                              hipStream_t stream) {
    const float* x    = (const float*)d_in[0];
    const float* grid = (const float*)d_in[1];
    const float* W0   = (const float*)d_in[2];
    const float* b0   = (const float*)d_in[3];
    const float* W1   = (const float*)d_in[4];
    const float* b1   = (const float*)d_in[5];
    float* out = (float*)d_out;

    const int N = in_sizes[0] / 3;
    const int blocks1 = (N + 255) / 256;

    const float2* gtab = (const float2*)grid;

    auto align256 = [](size_t v) { return (v + 255) & ~(size_t)255; };
    size_t off = 0;
    const size_t feat_off = off; off += align256((size_t)3 * N * 4);
    const size_t wt_off   = off; off += align256(1089 * 4);
    const size_t pk_off   = off; off += align256(36864 * 4);
    (void)ws_size;

    unsigned* feat   = (unsigned*)((char*)d_ws + feat_off);
    float*    wt     = (float*)((char*)d_ws + wt_off);
    unsigned* packed = (unsigned*)((char*)d_ws + pk_off);

    // Hash level 3 + prep (64 tail blocks).
    hash3_prep_kernel<<<blocks1 + 64, 256, 0, stream>>>(
        x, gtab, feat + (size_t)0 * N, N, wt, packed, W0, b0, W1, b1);
    hash_level_kernel<<<blocks1, 256, 0, stream>>>(x, gtab + 823296u,
                                                   feat + (size_t)1 * N, 255.0f, N);
    hash_level_kernel<<<blocks1, 256, 0, stream>>>(x, gtab + 1347584u,
                                                   feat + (size_t)2 * N, 511.0f, N);

    // Gate the 144KB-LDS path on what the runtime actually permits
    // (host-side queries: deterministic, graph-capture-safe).
    const size_t bigShm = 36864u * 4u;           // 147456 B
    const void* bigK =
        reinterpret_cast<const void*>(&dense_mlp_kernel<1024, true>);
    (void)hipFuncSetAttribute(bigK,
        hipFuncAttributeMaxDynamicSharedMemorySize, (int)bigShm);
    bool big = false;
    hipFuncAttributes fa{};
    if (hipFuncGetAttributes(&fa, bigK) == hipSuccess)
        big = ((size_t)fa.maxDynamicSharedSizeBytes >= bigShm);

    if (big) {
        const int blocksB = (N + 4095) / 4096;   // 1024 thr x 4 pts
        dense_mlp_kernel<1024, true><<<blocksB, 1024, bigShm, stream>>>(
            x, (const float*)grid, feat, wt, packed, out, N);
    } else {
        const int blocksF = (N + 1023) / 1024;   // 256 thr x 4 pts
        dense_mlp_kernel<256, false><<<blocksF, 256, 4096u * 4u, stream>>>(
            x, (const float*)grid, feat, wt, packed, out, N);
    }
}

// Round 13
// 313.085 us; speedup vs baseline: 1.9136x; 1.0168x over previous
//
#include <hip/hip_runtime.h>

// GridManifoldNetwork, round 13 = R11 dense_mlp (94.9us, scheduler-friendly
// straight-line form) + R12 prep-fold (-6us, verified). R12's phase-batching
// was falsified: VGPR 40 shows the compiler re-serialized the "batched"
// gathers and the restructure cost 10us. Two attempts (R3 asm, R12 phases)
// to beat the compiler's load scheduling both regressed -> keep R11 form.
//
// Composite model: hash 3x72.5us at the chip random-64B-line wall
// (~0.235M lines/us; sc0/merge/ILP/sort all falsified -> structural) +
// dense_mlp ~95us (VALU ~48us + level-2 line wall ~34us + residual stalls).
//
// Levels: res=16,32,64,128,256,512; F=2; T=2^19; levels 3..5 hashed,
// size 2^19 -> & 0x7FFFF. Entry offsets: 0,4096,36864,299008,823296,1347584.
// Levels 0+1 (entries [0,36864)) staged to LDS as packed bf16x2 (144KB).

#define HP1 2654435761u
#define HP2 805459861u
#define HMASK ((1u << 19) - 1u)

typedef float v2f __attribute__((ext_vector_type(2)));

static __device__ __forceinline__ unsigned umin_(unsigned a, unsigned b) {
    return a < b ? a : b;
}

// bf16 round-to-nearest-even pack/unpack.
static __device__ __forceinline__ unsigned f2bf(float f) {
    unsigned u = __float_as_uint(f);
    return (u + 0x7fffu + ((u >> 16) & 1u)) >> 16;
}
static __device__ __forceinline__ float bf2f_lo(unsigned p) {
    return __uint_as_float((p & 0xffffu) << 16);
}
static __device__ __forceinline__ float bf2f_hi(unsigned p) {
    return __uint_as_float(p & 0xffff0000u);
}

static __device__ __forceinline__ v2f vmax0(v2f s) {
#if __has_builtin(__builtin_elementwise_max)
    return __builtin_elementwise_max(s, (v2f)0.0f);
#else
    v2f r; r.x = fmaxf(s.x, 0.0f); r.y = fmaxf(s.y, 0.0f); return r;
#endif
}

// One hashed-level point block: 8 divergent 8B gathers + trilerp + bf16 pack.
static __device__ __forceinline__ void hash_body(
    const float* __restrict__ x, const float2* __restrict__ tab,
    unsigned* __restrict__ feat, float scale, int N, int bid)
{
    const int gid = bid * 256 + threadIdx.x;
    if (gid >= N) return;

    const float px = __builtin_nontemporal_load(x + 3 * gid + 0);
    const float py = __builtin_nontemporal_load(x + 3 * gid + 1);
    const float pz = __builtin_nontemporal_load(x + 3 * gid + 2);

    const float p0 = fmaf((px + 1.0f) * 0.5f, scale, 0.5f);
    const float p1 = fmaf((py + 1.0f) * 0.5f, scale, 0.5f);
    const float p2 = fmaf((pz + 1.0f) * 0.5f, scale, 0.5f);
    const float g0 = floorf(p0), g1 = floorf(p1), g2 = floorf(p2);
    const float f0 = p0 - g0, f1 = p1 - g1, f2 = p2 - g2;
    const unsigned i0 = (unsigned)g0, i1 = (unsigned)g1, i2 = (unsigned)g2;

    const float wx[2] = {1.0f - f0, f0};
    const float wy[2] = {1.0f - f1, f1};
    const float wz[2] = {1.0f - f2, f2};
    const unsigned hx[2] = {i0, i0 + 1u};
    const unsigned hy[2] = {i1 * HP1, (i1 + 1u) * HP1};
    const unsigned hz[2] = {i2 * HP2, (i2 + 1u) * HP2};

    unsigned idx[8];
    float w[8];
    #pragma unroll
    for (int c = 0; c < 8; ++c) {
        const int bx = c & 1, by = (c >> 1) & 1, bz = (c >> 2) & 1;
        idx[c] = (hx[bx] ^ hy[by] ^ hz[bz]) & HMASK;
        w[c] = wx[bx] * wy[by] * wz[bz];
    }
    float2 v[8];
    #pragma unroll
    for (int c = 0; c < 8; ++c) v[c] = tab[idx[c]];

    float a0 = 0.0f, a1 = 0.0f;
    #pragma unroll
    for (int c = 0; c < 8; ++c) {
        a0 = fmaf(w[c], v[c].x, a0);
        a1 = fmaf(w[c], v[c].y, a1);
    }
    __builtin_nontemporal_store(f2bf(a0) | (f2bf(a1) << 16), feat + gid);
}

// Hash level 3 + prep folded into 64 tail blocks.
__global__ __launch_bounds__(256) void hash3_prep_kernel(
    const float* __restrict__ x, const float2* __restrict__ gtab,
    unsigned* __restrict__ feat0, int N,
    float* __restrict__ wt, unsigned* __restrict__ packed,
    const float* __restrict__ W0, const float* __restrict__ b0,
    const float* __restrict__ W1, const float* __restrict__ b1)
{
    const int nh = (int)gridDim.x - 64;
    if ((int)blockIdx.x >= nh) {
        const int pb = (int)blockIdx.x - nh;   // 0..63
        for (int t = pb * 256 + threadIdx.x; t < 36864; t += 64 * 256) {
            const float2 e = gtab[t];
            packed[t] = f2bf(e.x) | (f2bf(e.y) << 16);
        }
        if (pb == 0) {
            for (int t = threadIdx.x; t < 1024; t += 256) {
                const int j = t >> 4, i = t & 15;
                wt[t] = (i == 15) ? b0[j] : W0[i * 64 + j];
            }
            if (threadIdx.x < 64) wt[1024 + threadIdx.x] = W1[threadIdx.x];
            if (threadIdx.x == 0) wt[1088] = b1[0];
        }
        return;
    }
    hash_body(x, gtab + 299008u, feat0, 127.0f, N, (int)blockIdx.x);
}

__global__ __launch_bounds__(256) void hash_level_kernel(
    const float* __restrict__ x, const float2* __restrict__ tab,
    unsigned* __restrict__ feat, float scale, int N)
{
    hash_body(x, tab, feat, scale, N, (int)blockIdx.x);
}

// Dense trilinear level from global fp32 float2 (level 2; R11 form).
static __device__ __forceinline__ void dense_level(
    const float2* __restrict__ tab, unsigned res,
    float xn0, float xn1, float xn2, float& o0, float& o1)
{
    const float scale = (float)(res - 1);
    const float p0 = fmaf(xn0, scale, 0.5f);
    const float p1 = fmaf(xn1, scale, 0.5f);
    const float p2 = fmaf(xn2, scale, 0.5f);
    const float g0 = floorf(p0), g1 = floorf(p1), g2 = floorf(p2);
    const float f0 = p0 - g0, f1 = p1 - g1, f2 = p2 - g2;
    const unsigned i0 = (unsigned)g0, i1 = (unsigned)g1, i2 = (unsigned)g2;

    const unsigned rm1 = res - 1u;
    const unsigned cx[2] = {umin_(i0, rm1), umin_(i0 + 1u, rm1)};
    const unsigned cy[2] = {umin_(i1, rm1) * res, umin_(i1 + 1u, rm1) * res};
    const unsigned cz[2] = {umin_(i2, rm1) * res * res,
                            umin_(i2 + 1u, rm1) * res * res};
    const float wx[2] = {1.0f - f0, f0};
    const float wy[2] = {1.0f - f1, f1};
    const float wz[2] = {1.0f - f2, f2};

    float a0 = 0.0f, a1 = 0.0f;
    #pragma unroll
    for (int c = 0; c < 8; ++c) {
        const int bx = c & 1, by = (c >> 1) & 1, bz = (c >> 2) & 1;
        const unsigned idx = cx[bx] + cy[by] + cz[bz];
        const float w = wx[bx] * wy[by] * wz[bz];
        const float2 v = tab[idx];
        a0 = fmaf(w, v.x, a0);
        a1 = fmaf(w, v.y, a1);
    }
    o0 = a0;
    o1 = a1;
}

// Dense trilinear level from LDS-resident packed bf16x2 table (R11 form).
static __device__ __forceinline__ void dense_level_lds(
    const unsigned* __restrict__ sPk, unsigned off, unsigned res,
    float xn0, float xn1, float xn2, float& o0, float& o1)
{
    const float scale = (float)(res - 1);
    const float p0 = fmaf(xn0, scale, 0.5f);
    const float p1 = fmaf(xn1, scale, 0.5f);
    const float p2 = fmaf(xn2, scale, 0.5f);
    const float g0 = floorf(p0), g1 = floorf(p1), g2 = floorf(p2);
    const float f0 = p0 - g0, f1 = p1 - g1, f2 = p2 - g2;
    const unsigned i0 = (unsigned)g0, i1 = (unsigned)g1, i2 = (unsigned)g2;

    const unsigned rm1 = res - 1u;
    const unsigned cx[2] = {umin_(i0, rm1), umin_(i0 + 1u, rm1)};
    const unsigned cy[2] = {umin_(i1, rm1) * res, umin_(i1 + 1u, rm1) * res};
    const unsigned cz[2] = {umin_(i2, rm1) * res * res,
                            umin_(i2 + 1u, rm1) * res * res};
    const float wx[2] = {1.0f - f0, f0};
    const float wy[2] = {1.0f - f1, f1};
    const float wz[2] = {1.0f - f2, f2};

    float a0 = 0.0f, a1 = 0.0f;
    #pragma unroll
    for (int c = 0; c < 8; ++c) {
        const int bx = c & 1, by = (c >> 1) & 1, bz = (c >> 2) & 1;
        const unsigned p = sPk[off + cx[bx] + cy[by] + cz[bz]];
        const float w = wx[bx] * wy[by] * wz[bz];
        a0 = fmaf(w, bf2f_lo(p), a0);
        a1 = fmaf(w, bf2f_hi(p), a1);
    }
    o0 = a0;
    o1 = a1;
}

// Dense levels + MLP, 4 points/thread (R11 form verbatim). L1LDS=true:
// levels 0+1 from 144KB LDS; false: level 0 only. Level 2 via TCP.
// Weights via SMEM pipe; MLP over 2-pt v2f pairs -> v_pk_fma_f32.
template<int BLOCK, bool L1LDS>
__global__ __launch_bounds__(BLOCK, 4) void dense_mlp_kernel(
    const float* __restrict__ x,
    const float* __restrict__ grid,
    const unsigned* __restrict__ feat,   // [3][N] packed bf16x2
    const float* __restrict__ wt,        // 1089 floats
    const unsigned* __restrict__ packed, // 36864 bf16x2 words (levels 0+1)
    float* __restrict__ out, int N)
{
    extern __shared__ unsigned sPk[];
    const int tid = threadIdx.x;

    const int nstage = L1LDS ? 36864 : 4096;
    for (int t = tid; t < nstage; t += BLOCK)
        sPk[t] = packed[t];
    __syncthreads();

    const int base = blockIdx.x * (BLOCK * 4) + tid;
    const float2* gtab = (const float2*)grid;

    // hp[p][i] = {feature i of point 2p, feature i of point 2p+1}
    v2f hp[2][16];

    #pragma unroll
    for (int k = 0; k < 4; ++k) {
        const int g = base + BLOCK * k;
        const int gs = (g < N) ? g : 0;
        const int p = k >> 1, lane = k & 1;

        const float px = __builtin_nontemporal_load(x + 3 * gs + 0);
        const float py = __builtin_nontemporal_load(x + 3 * gs + 1);
        const float pz = __builtin_nontemporal_load(x + 3 * gs + 2);
        const float xn0 = (px + 1.0f) * 0.5f;
        const float xn1 = (py + 1.0f) * 0.5f;
        const float xn2 = (pz + 1.0f) * 0.5f;

        hp[p][0][lane] = px; hp[p][1][lane] = py; hp[p][2][lane] = pz;
        hp[p][15][lane] = 1.0f;

        float t3, t4, t5, t6, t7, t8;
        dense_level_lds(sPk, 0u, 16u, xn0, xn1, xn2, t3, t4);
        if (L1LDS)
            dense_level_lds(sPk, 4096u, 32u, xn0, xn1, xn2, t5, t6);
        else
            dense_level(gtab + 4096u, 32u, xn0, xn1, xn2, t5, t6);
        dense_level(gtab + 36864u, 64u, xn0, xn1, xn2, t7, t8);
        hp[p][3][lane] = t3; hp[p][4][lane] = t4;
        hp[p][5][lane] = t5; hp[p][6][lane] = t6;
        hp[p][7][lane] = t7; hp[p][8][lane] = t8;

        #pragma unroll
        for (int l = 0; l < 3; ++l) {
            const unsigned pk = __builtin_nontemporal_load(
                feat + (size_t)l * N + gs);
            hp[p][9 + 2 * l][lane]  = bf2f_lo(pk);
            hp[p][10 + 2 * l][lane] = bf2f_hi(pk);
        }
    }

    // MLP: out = relu(h @ W0 + b0) @ W1 + b1 (bias folded via h[15]=1).
    const float b1v = wt[1088];
    v2f o2[2];
    o2[0] = (v2f)b1v; o2[1] = (v2f)b1v;

    #pragma unroll 4
    for (int j = 0; j < 64; ++j) {
        float r[16];
        #pragma unroll
        for (int i = 0; i < 16; ++i)
            r[i] = wt[j * 16 + i];          // uniform -> s_load (SMEM pipe)
        const float w1j = wt[1024 + j];
        #pragma unroll
        for (int p = 0; p < 2; ++p) {
            v2f s = (v2f)0.0f;
            #pragma unroll
            for (int i = 0; i < 16; ++i)
                s = hp[p][i] * r[i] + s;     // v_pk_fma_f32
            s = vmax0(s);
            o2[p] = s * w1j + o2[p];
        }
    }

    #pragma unroll
    for (int k = 0; k < 4; ++k) {
        const int g = base + BLOCK * k;
        if (g < N)
            __builtin_nontemporal_store(o2[k >> 1][k & 1], out + g);
    }
}

extern "C" void kernel_launch(void* const* d_in, const int* in_sizes, int n_in,
                              void* d_out, int out_size, void* d_ws, size_t ws_size,
                              hipStream_t stream) {
    const float* x    = (const float*)d_in[0];
    const float* grid = (const float*)d_in[1];
    const float* W0   = (const float*)d_in[2];
    const float* b0   = (const float*)d_in[3];
    const float* W1   = (const float*)d_in[4];
    const float* b1   = (const float*)d_in[5];
    float* out = (float*)d_out;

    const int N = in_sizes[0] / 3;
    const int blocks1 = (N + 255) / 256;

    const float2* gtab = (const float2*)grid;

    auto align256 = [](size_t v) { return (v + 255) & ~(size_t)255; };
    size_t off = 0;
    const size_t feat_off = off; off += align256((size_t)3 * N * 4);
    const size_t wt_off   = off; off += align256(1089 * 4);
    const size_t pk_off   = off; off += align256(36864 * 4);
    (void)ws_size;

    unsigned* feat   = (unsigned*)((char*)d_ws + feat_off);
    float*    wt     = (float*)((char*)d_ws + wt_off);
    unsigned* packed = (unsigned*)((char*)d_ws + pk_off);

    // Hash level 3 + prep (64 tail blocks).
    hash3_prep_kernel<<<blocks1 + 64, 256, 0, stream>>>(
        x, gtab, feat + (size_t)0 * N, N, wt, packed, W0, b0, W1, b1);
    hash_level_kernel<<<blocks1, 256, 0, stream>>>(x, gtab + 823296u,
                                                   feat + (size_t)1 * N, 255.0f, N);
    hash_level_kernel<<<blocks1, 256, 0, stream>>>(x, gtab + 1347584u,
                                                   feat + (size_t)2 * N, 511.0f, N);

    // Gate the 144KB-LDS path on what the runtime actually permits
    // (host-side queries: deterministic, graph-capture-safe).
    const size_t bigShm = 36864u * 4u;           // 147456 B
    const void* bigK =
        reinterpret_cast<const void*>(&dense_mlp_kernel<1024, true>);
    (void)hipFuncSetAttribute(bigK,
        hipFuncAttributeMaxDynamicSharedMemorySize, (int)bigShm);
    bool big = false;
    hipFuncAttributes fa{};
    if (hipFuncGetAttributes(&fa, bigK) == hipSuccess)
        big = ((size_t)fa.maxDynamicSharedSizeBytes >= bigShm);

    if (big) {
        const int blocksB = (N + 4095) / 4096;   // 1024 thr x 4 pts
        dense_mlp_kernel<1024, true><<<blocksB, 1024, bigShm, stream>>>(
            x, (const float*)grid, feat, wt, packed, out, N);
    } else {
        const int blocksF = (N + 1023) / 1024;   // 256 thr x 4 pts
        dense_mlp_kernel<256, false><<<blocksF, 256, 4096u * 4u, stream>>>(
            x, (const float*)grid, feat, wt, packed, out, N);
    }
}